// Round 5
// baseline (11096.538 us; speedup 1.0000x reference)
//
#include <hip/hip_runtime.h>
#include <stdint.h>

typedef unsigned short ushort_t;
typedef unsigned long long u64;
typedef __attribute__((ext_vector_type(8))) short short8;
typedef __attribute__((ext_vector_type(4))) float f32x4;

#define T_SEQ 3300
#define SENT 0x7FC00001u
#define OUT_BYTES 108134400ull   // 16*3300*512*4

__device__ __forceinline__ ushort_t f2b(float f) {
  uint32_t u = __float_as_uint(f);
  u = (u + 0x7fffu + ((u >> 16) & 1u)) >> 16;
  return (ushort_t)u;
}
__device__ __forceinline__ float b2f(ushort_t b) {
  return __uint_as_float(((uint32_t)b) << 16);
}

// ---------------- prep: weight conversions + ring sentinel init -------------
// Segments (i = global thread):
//   [0, 786432)        w_ihT[d][g] = bf16(w_ih[g][d])            (one-hot rows)
//   [786432, 1572864)  whh_hi/lo   = bf16x2 split of w_hh        (row-major)
//   [1572864, 1720320) wmel_hi/lo  = bf16x2 split of w_ih[:,512:592], K-pad 96
//   [1720320, 1982464) fc1wb
//   [1982464, 2244608) fc2wb
//   [2244608, 2375680) h_ring sentinel (agent-scope store)
__global__ void prep_kernel(const float* __restrict__ w_ih,
                            const float* __restrict__ w_hh,
                            const float* __restrict__ fc1w,
                            const float* __restrict__ fc2w,
                            ushort_t* __restrict__ w_ihT,
                            ushort_t* __restrict__ whh_hi,
                            ushort_t* __restrict__ whh_lo,
                            ushort_t* __restrict__ wmel_hi,
                            ushort_t* __restrict__ wmel_lo,
                            ushort_t* __restrict__ fc1wb,
                            ushort_t* __restrict__ fc2wb,
                            uint32_t* __restrict__ h_ring) {
  int i = blockIdx.x * 256 + threadIdx.x;
  if (i < 786432) {
    int d = i / 1536, g = i - d * 1536;
    w_ihT[i] = f2b(w_ih[g * 592 + d]);
  }
  int a = i - 786432;
  if (a >= 0 && a < 786432) {
    float v = w_hh[a];
    ushort_t h = f2b(v);
    whh_hi[a] = h;
    whh_lo[a] = f2b(v - b2f(h));
  }
  int m = a - 786432;
  if (m >= 0 && m < 147456) {
    int g = m / 96, f = m - g * 96;
    float v = (f < 80) ? w_ih[g * 592 + 512 + f] : 0.f;
    ushort_t h = f2b(v);
    wmel_hi[m] = h;
    wmel_lo[m] = f2b(v - b2f(h));
  }
  int j = m - 147456;
  if (j >= 0 && j < 262144) fc1wb[j] = f2b(fc1w[j]);
  int k = j - 262144;
  if (k >= 0 && k < 262144) fc2wb[k] = f2b(fc2w[k]);
  int c = k - 262144;
  if (c >= 0 && c < 131072) {
    __hip_atomic_store(&h_ring[c], SENT, __ATOMIC_RELAXED, __HIP_MEMORY_SCOPE_AGENT);
  }
}

// ---------------- upsample: repeat+box-filter cascade, one block per (b,f) --
// Output layout TRANSPOSED to [t][b][f] so the GRU's per-step mel read is a
// single contiguous 5 KB slab.
__global__ void upsample_kernel(const float* __restrict__ mels,
                                const float* __restrict__ k0,
                                const float* __restrict__ k1,
                                const float* __restrict__ k2,
                                float* __restrict__ mels_upT) {
  __shared__ float s0[16];
  __shared__ float s1[80];
  __shared__ float s2[400];
  int bf = blockIdx.x;
  int b = bf / 80, f = bf - b * 80;
  int tid = threadIdx.x;  // 128
  float c0 = k0[0], c1 = k1[0], c2 = k2[0];
  if (tid < 16) s0[tid] = mels[(b * 80 + f) * 16 + tid];
  __syncthreads();
  if (tid < 80) {
    float a = 0.f;
    #pragma unroll
    for (int d = -5; d <= 5; ++d) {
      int w = tid + d;
      if (w >= 0 && w < 80) a += s0[w / 5];
    }
    s1[tid] = a * c0;
  }
  __syncthreads();
  for (int w = tid; w < 400; w += 128) {
    float a = 0.f;
    #pragma unroll
    for (int d = -5; d <= 5; ++d) {
      int u = w + d;
      if (u >= 0 && u < 400) a += s1[u / 5];
    }
    s2[w] = a * c1;
  }
  __syncthreads();
  for (int t = tid; t < T_SEQ; t += 128) {
    int wb = 550 + t;   // wb+d in [539,3860] -> /11 < 400: no bounds needed
    float a = 0.f;
    #pragma unroll
    for (int d = -11; d <= 11; ++d) a += s2[(wb + d) / 11];
    mels_upT[t * 1280 + b * 80 + f] = a * c2;
  }
}

// ---------------- persistent GRU, MFMA edition ------------------------------
// 32 blocks x 512 threads. Block owns h dims [16*blk, 16*blk+16) for ALL 16
// batches. Per step: gate pre-activations = 16x48x512 GEMM via 16x16x32 bf16
// MFMA with bf16x3 splitting (Whi,Wlo x Hhi,Hlo minus lo*lo) => ~fp32 accurate.
// Wave map: wv=0..5 -> (nt=wv>>1 gate-tile, kh=wv&1 K-half, 24 MFMA each);
// wv=6 -> mel tiles r,z; wv=7 -> mel tile n (K=96, 9 MFMA per tile).
// Gate math: 256 threads (b,d), h_prev register-resident.
// Cross-block h exchange: proven 16-slot relaxed-AGENT ring; each h value is
// one u32 (bf16 hi | lo<<16); sentinel u32 impossible for real data (lo half
// 0x7FC0 would be NaN). Re-arm slot t+8 as in baseline. Poll bounded (no hang).
__global__ __launch_bounds__(512) void gru_kernel(
    const int* __restrict__ x,
    const float* __restrict__ mels_upT,   // [t][16][80]
    const float* __restrict__ b_ih,
    const float* __restrict__ b_hh,
    const ushort_t* __restrict__ w_ihT,   // [512][1536] bf16
    const ushort_t* __restrict__ whh_hi,  // [1536][512] bf16
    const ushort_t* __restrict__ whh_lo,
    const ushort_t* __restrict__ wmel_hi, // [1536][96] bf16
    const ushort_t* __restrict__ wmel_lo,
    uint32_t* __restrict__ h_ring,        // [16][16][512] u32 (hi|lo<<16)
    ushort_t* __restrict__ h_seq)         // [16][3300][512] bf16
{
  int blk = blockIdx.x;        // 0..31
  int tid = threadIdx.x;
  int lane = tid & 63, wv = tid >> 6;
  int lm = lane & 15, lq = lane >> 4;
  int pb = tid >> 5, pc = tid & 31;       // poll/stage mapping: batch, chunk
  int gb = tid >> 4, gd = tid & 15;       // gate mapping (tid<256)

  __shared__ __align__(16) ushort_t Hhi[16][520];   // rows padded: 2-way banks
  __shared__ __align__(16) ushort_t Hlo[16][520];
  __shared__ __align__(16) ushort_t Mhi[16][104];
  __shared__ __align__(16) ushort_t Mlo[16][104];
  __shared__ float Cred[9][16][16];
  __shared__ int xvbuf[16];

  // zero mel K-pad once (cols 80..104 never rewritten)
  for (int idx = tid; idx < 16 * 24; idx += 512) {
    int b = idx / 24, f = 80 + (idx - b * 24);
    Mhi[b][f] = 0; Mlo[b][f] = 0;
  }

  // ---- resident W fragments (B-operand layout == head_kernel's pattern) ----
  int nt = wv >> 1, kh = wv & 1;
  short8 wbh[8], wbl[8];
  if (wv < 6) {
    int row = nt * 512 + blk * 16 + lm;
    #pragma unroll
    for (int k8 = 0; k8 < 8; ++k8) {
      int kt = kh * 8 + k8;
      wbh[k8] = *(const short8*)(whh_hi + (size_t)row * 512 + kt * 32 + lq * 8);
      wbl[k8] = *(const short8*)(whh_lo + (size_t)row * 512 + kt * 32 + lq * 8);
    }
  }
  short8 wmh[2][3], wml[2][3];
  if (wv >= 6) {
    #pragma unroll
    for (int u = 0; u < 2; ++u) {
      int nt2 = (wv == 6) ? u : 2;
      int row = nt2 * 512 + blk * 16 + lm;
      #pragma unroll
      for (int kt = 0; kt < 3; ++kt) {
        wmh[u][kt] = *(const short8*)(wmel_hi + (size_t)row * 96 + kt * 32 + lq * 8);
        wml[u][kt] = *(const short8*)(wmel_lo + (size_t)row * 96 + kt * 32 + lq * 8);
      }
    }
  }
  // gate-thread constants + register-resident h
  float h_prev = 0.f, bsr = 0.f, bsz = 0.f, bihn_ = 0.f, bhhn_ = 0.f;
  if (tid < 256) {
    int gr = blk * 16 + gd;
    bsr = b_ih[gr] + b_hh[gr];
    bsz = b_ih[512 + gr] + b_hh[512 + gr];
    bihn_ = b_ih[1024 + gr];
    bhhn_ = b_hh[1024 + gr];
  }

  for (int t = 0; t < T_SEQ; ++t) {
    int rslot = (t - 1) & 15, wslot = t & 15, aslot = (t + 8) & 15;
    // ================= phase A: prefetch + poll + stage =================
    f32x4 ma = {0.f, 0.f, 0.f, 0.f}, mb = {0.f, 0.f, 0.f, 0.f};
    if (tid < 160) {
      const float* mp = mels_upT + (size_t)t * 1280 + tid * 8;
      ma = *(const f32x4*)mp;
      mb = *(const f32x4*)(mp + 4);
    }
    if (tid < 16) xvbuf[tid] = x[tid * T_SEQ + t];

    u64 q[8];
    #pragma unroll
    for (int jj = 0; jj < 8; ++jj) q[jj] = 0;
    if (t > 0) {
      const u64* src = (const u64*)&h_ring[((rslot * 16 + pb) << 9) + pc * 16];
      // escape hatch: legit waits are a couple of iters; exhaustion leaves NaN
      // sentinels in the data (visible absmax failure) instead of a hang.
      for (int spin = 0; spin < 4096; ++spin) {
        bool ok = true;
        #pragma unroll
        for (int jj = 0; jj < 8; ++jj) {
          q[jj] = __hip_atomic_load(src + jj, __ATOMIC_RELAXED, __HIP_MEMORY_SCOPE_AGENT);
          ok = ok && (((uint32_t)q[jj]) != SENT) && (((uint32_t)(q[jj] >> 32)) != SENT);
        }
        if (ok) break;
      }
    }
    {  // unpack (hi|lo<<16) pairs into Hhi/Hlo rows
      uint32_t* hrow = (uint32_t*)&Hhi[pb][0];
      uint32_t* lrow = (uint32_t*)&Hlo[pb][0];
      #pragma unroll
      for (int jj = 0; jj < 8; ++jj) {
        uint32_t w0 = (uint32_t)q[jj], w1 = (uint32_t)(q[jj] >> 32);
        hrow[pc * 8 + jj] = (w0 & 0xFFFFu) | (w1 << 16);
        lrow[pc * 8 + jj] = (w0 >> 16) | (w1 & 0xFFFF0000u);
      }
    }
    if (tid < 160) {  // mel hi/lo split + stage
      short8 hv, lv;
      #pragma unroll
      for (int e = 0; e < 4; ++e) {
        ushort_t h0 = f2b(ma[e]);
        hv[e] = (short)h0; lv[e] = (short)f2b(ma[e] - b2f(h0));
        ushort_t h1 = f2b(mb[e]);
        hv[4 + e] = (short)h1; lv[4 + e] = (short)f2b(mb[e] - b2f(h1));
      }
      int mbb = tid / 10, mf = (tid - mbb * 10) * 8;
      *(short8*)&Mhi[mbb][mf] = hv;
      *(short8*)&Mlo[mbb][mf] = lv;
    }
    __syncthreads();

    // ================= phase B: MFMA + emb prefetch =================
    float embr = 0.f, embz = 0.f, embn = 0.f;
    if (tid < 256) {
      int xv = xvbuf[gb];
      const ushort_t* er = w_ihT + (size_t)xv * 1536 + blk * 16 + gd;
      embr = b2f(er[0]);
      embz = b2f(er[512]);
      embn = b2f(er[1024]);
    }
    if (wv < 6) {
      short8 ah[8], al[8];
      #pragma unroll
      for (int k8 = 0; k8 < 8; ++k8) {
        int kk = (kh * 8 + k8) * 32 + lq * 8;
        ah[k8] = *(const short8*)&Hhi[lm][kk];
        al[k8] = *(const short8*)&Hlo[lm][kk];
      }
      f32x4 ce = {0.f, 0.f, 0.f, 0.f}, co = {0.f, 0.f, 0.f, 0.f};
      #pragma unroll
      for (int k8 = 0; k8 < 8; ++k8) {
        ce = __builtin_amdgcn_mfma_f32_16x16x32_bf16(ah[k8], wbh[k8], ce, 0, 0, 0);
        co = __builtin_amdgcn_mfma_f32_16x16x32_bf16(al[k8], wbh[k8], co, 0, 0, 0);
        ce = __builtin_amdgcn_mfma_f32_16x16x32_bf16(ah[k8], wbl[k8], ce, 0, 0, 0);
      }
      #pragma unroll
      for (int r = 0; r < 4; ++r) Cred[wv][lq * 4 + r][lm] = ce[r] + co[r];
    } else {
      short8 amh[3], aml[3];
      #pragma unroll
      for (int kt = 0; kt < 3; ++kt) {
        amh[kt] = *(const short8*)&Mhi[lm][kt * 32 + lq * 8];
        aml[kt] = *(const short8*)&Mlo[lm][kt * 32 + lq * 8];
      }
      #pragma unroll
      for (int u = 0; u < 2; ++u) {
        if (!(wv == 7 && u == 1)) {
          f32x4 cm = {0.f, 0.f, 0.f, 0.f};
          #pragma unroll
          for (int kt = 0; kt < 3; ++kt) {
            cm = __builtin_amdgcn_mfma_f32_16x16x32_bf16(amh[kt], wmh[u][kt], cm, 0, 0, 0);
            cm = __builtin_amdgcn_mfma_f32_16x16x32_bf16(aml[kt], wmh[u][kt], cm, 0, 0, 0);
            cm = __builtin_amdgcn_mfma_f32_16x16x32_bf16(amh[kt], wml[u][kt], cm, 0, 0, 0);
          }
          int cslot = (wv == 6) ? (6 + u) : 8;
          #pragma unroll
          for (int r = 0; r < 4; ++r) Cred[cslot][lq * 4 + r][lm] = cm[r];
        }
      }
    }
    __syncthreads();

    // ================= phase C: gates + publish =================
    if (tid < 256) {
      float hr = Cred[0][gb][gd] + Cred[1][gb][gd];
      float hz = Cred[2][gb][gd] + Cred[3][gb][gd];
      float hn = Cred[4][gb][gd] + Cred[5][gb][gd];
      float mr = Cred[6][gb][gd], mz = Cred[7][gb][gd], mn = Cred[8][gb][gd];
      float ar = embr + mr + hr + bsr;
      float az = embz + mz + hz + bsz;
      float rg = 1.f / (1.f + __expf(-ar));
      float zg = 1.f / (1.f + __expf(-az));
      float xn = embn + mn + bihn_;
      float hns = hn + bhhn_;
      float na = xn + rg * hns;
      float e2 = __expf(2.f * na);
      float ng = 1.f - 2.f / (e2 + 1.f);   // tanh
      float h = (1.f - zg) * ng + zg * h_prev;
      h_prev = h;
      ushort_t hib = f2b(h);
      ushort_t lob = f2b(h - b2f(hib));
      uint32_t pk = (uint32_t)hib | ((uint32_t)lob << 16);
      __hip_atomic_store(&h_ring[((wslot * 16 + gb) << 9) + blk * 16 + gd], pk,
                         __ATOMIC_RELAXED, __HIP_MEMORY_SCOPE_AGENT);
      // re-arm slot t+8 (next written at t+8, last read at t-7; same-thread
      // same-address order preserved by per-step vmcnt drains at barriers)
      __hip_atomic_store(&h_ring[((aslot * 16 + gb) << 9) + blk * 16 + gd], SENT,
                         __ATOMIC_RELAXED, __HIP_MEMORY_SCOPE_AGENT);
      h_seq[(size_t)(gb * T_SEQ + t) * 512 + blk * 16 + gd] = hib;
    }
    __syncthreads();
  }
}

// ---------------- fused head: relu(h*fc1^T+b1)*fc2^T+b2 via bf16 MFMA -------
__global__ __launch_bounds__(512) void head_kernel(
    const ushort_t* __restrict__ h_seq,
    const ushort_t* __restrict__ fc1w,   // [n][k] bf16
    const ushort_t* __restrict__ fc2w,   // [n][k] bf16
    const float* __restrict__ fc1b,
    const float* __restrict__ fc2b,
    float* __restrict__ out) {
  __shared__ __align__(16) ushort_t h1[64 * 512];
  int blk = blockIdx.x;          // 825 blocks, 64 rows each
  int tid = threadIdx.x;
  int w = tid >> 6, l = tid & 63;
  int lm = l & 15, lq = l >> 4;
  int mt = w & 3;                // m-tile within the 64-row block
  int nb = (w >> 2) * 256;       // this wave's n-range
  int m0 = blk * 64;

  f32x4 acc[16];
  #pragma unroll
  for (int i = 0; i < 16; ++i) acc[i] = (f32x4){0.f, 0.f, 0.f, 0.f};
  const ushort_t* arow = h_seq + (size_t)(m0 + mt * 16 + lm) * 512;
  for (int kt = 0; kt < 16; ++kt) {
    short8 a = *(const short8*)(arow + kt * 32 + lq * 8);
    #pragma unroll
    for (int nt = 0; nt < 16; ++nt) {
      short8 bb = *(const short8*)(fc1w + (size_t)(nb + nt * 16 + lm) * 512 + kt * 32 + lq * 8);
      acc[nt] = __builtin_amdgcn_mfma_f32_16x16x32_bf16(a, bb, acc[nt], 0, 0, 0);
    }
  }
  #pragma unroll
  for (int nt = 0; nt < 16; ++nt) {
    int n = nb + nt * 16 + lm;
    float bias = fc1b[n];
    #pragma unroll
    for (int r = 0; r < 4; ++r) {
      int m = mt * 16 + lq * 4 + r;
      float vv = acc[nt][r] + bias;
      vv = fmaxf(vv, 0.f);
      h1[m * 512 + n] = f2b(vv);
    }
  }
  __syncthreads();
  f32x4 acc2[16];
  #pragma unroll
  for (int i = 0; i < 16; ++i) acc2[i] = (f32x4){0.f, 0.f, 0.f, 0.f};
  for (int kt = 0; kt < 16; ++kt) {
    short8 a = *(const short8*)&h1[(mt * 16 + lm) * 512 + kt * 32 + lq * 8];
    #pragma unroll
    for (int nt = 0; nt < 16; ++nt) {
      short8 bb = *(const short8*)(fc2w + (size_t)(nb + nt * 16 + lm) * 512 + kt * 32 + lq * 8);
      acc2[nt] = __builtin_amdgcn_mfma_f32_16x16x32_bf16(a, bb, acc2[nt], 0, 0, 0);
    }
  }
  #pragma unroll
  for (int nt = 0; nt < 16; ++nt) {
    int n = nb + nt * 16 + lm;
    float bias = fc2b[n];
    #pragma unroll
    for (int r = 0; r < 4; ++r) {
      int m = mt * 16 + lq * 4 + r;
      out[(size_t)(m0 + m) * 512 + n] = acc2[nt][r] + bias;
    }
  }
}

// ---------------- launch -----------------------------------------------------
extern "C" void kernel_launch(void* const* d_in, const int* in_sizes, int n_in,
                              void* d_out, int out_size, void* d_ws, size_t ws_size,
                              hipStream_t stream) {
  (void)in_sizes; (void)n_in; (void)out_size; (void)ws_size;
  const int*   x    = (const int*)d_in[0];
  const float* mels = (const float*)d_in[1];
  const float* k0   = (const float*)d_in[2];
  const float* k1   = (const float*)d_in[3];
  const float* k2   = (const float*)d_in[4];
  const float* w_ih = (const float*)d_in[5];
  const float* w_hh = (const float*)d_in[6];
  const float* b_ih = (const float*)d_in[7];
  const float* b_hh = (const float*)d_in[8];
  const float* fc1w = (const float*)d_in[9];
  const float* fc1b = (const float*)d_in[10];
  const float* fc2w = (const float*)d_in[11];
  const float* fc2b = (const float*)d_in[12];

  char* ws = (char*)d_ws;   // footprint identical to the proven baseline
  float*    mels_upT = (float*)(ws + 0);           // 3300*1280*4   = 16,896,000
  ushort_t* h_seq    = (ushort_t*)(ws + 16896000); // 16*3300*512*2 = 54,067,200
  ushort_t* w_ihT    = (ushort_t*)(ws + 70963200); // 512*1536*2    =  1,572,864
  ushort_t* fc1wb    = (ushort_t*)(ws + 72536064); // 512*512*2     =    524,288
  ushort_t* fc2wb    = (ushort_t*)(ws + 73060352); // 512*512*2     =    524,288
  uint32_t* h_ring   = (uint32_t*)(ws + 73584640); // 16*16*512*4   =    524,288

  // Split-weight scratch (3,735,552 B) lives in the TAIL of d_out: written by
  // prep every run, read only by gru, overwritten by head afterwards.
  char* ob = (char*)d_out;
  ushort_t* whh_hi  = (ushort_t*)(ob + OUT_BYTES - 3735552); // 1,572,864
  ushort_t* whh_lo  = (ushort_t*)(ob + OUT_BYTES - 2162688); // 1,572,864
  ushort_t* wmel_hi = (ushort_t*)(ob + OUT_BYTES -  589824); //   294,912
  ushort_t* wmel_lo = (ushort_t*)(ob + OUT_BYTES -  294912); //   294,912

  prep_kernel<<<9280, 256, 0, stream>>>(w_ih, w_hh, fc1w, fc2w, w_ihT,
                                        whh_hi, whh_lo, wmel_hi, wmel_lo,
                                        fc1wb, fc2wb, h_ring);
  upsample_kernel<<<1280, 128, 0, stream>>>(mels, k0, k1, k2, mels_upT);
  gru_kernel<<<32, 512, 0, stream>>>(x, mels_upT, b_ih, b_hh, w_ihT,
                                     whh_hi, whh_lo, wmel_hi, wmel_lo,
                                     h_ring, h_seq);
  head_kernel<<<825, 512, 0, stream>>>(h_seq, fc1wb, fc2wb, fc1b, fc2b, (float*)d_out);
}

// Round 6
// 8516.911 us; speedup vs baseline: 1.3029x; 1.3029x over previous
//
#include <hip/hip_runtime.h>
#include <stdint.h>

typedef unsigned short ushort_t;
typedef unsigned long long u64;
typedef __attribute__((ext_vector_type(8))) short short8;
typedef __attribute__((ext_vector_type(4))) float f32x4;

#define T_SEQ 3300
#define SENT 0x7FC00001u
#define OUT_BYTES 108134400ull   // 16*3300*512*4

__device__ __forceinline__ ushort_t f2b(float f) {
  uint32_t u = __float_as_uint(f);
  u = (u + 0x7fffu + ((u >> 16) & 1u)) >> 16;
  return (ushort_t)u;
}
__device__ __forceinline__ float b2f(ushort_t b) {
  return __uint_as_float(((uint32_t)b) << 16);
}

// ---------------- prep: weight conversions + ring sentinel init -------------
__global__ void prep_kernel(const float* __restrict__ w_ih,
                            const float* __restrict__ w_hh,
                            const float* __restrict__ fc1w,
                            const float* __restrict__ fc2w,
                            ushort_t* __restrict__ w_ihT,
                            ushort_t* __restrict__ whh_hi,
                            ushort_t* __restrict__ whh_lo,
                            ushort_t* __restrict__ wmel_hi,
                            ushort_t* __restrict__ wmel_lo,
                            ushort_t* __restrict__ fc1wb,
                            ushort_t* __restrict__ fc2wb,
                            uint32_t* __restrict__ h_ring) {
  int i = blockIdx.x * 256 + threadIdx.x;
  if (i < 786432) {
    int d = i / 1536, g = i - d * 1536;
    w_ihT[i] = f2b(w_ih[g * 592 + d]);
  }
  int a = i - 786432;
  if (a >= 0 && a < 786432) {
    float v = w_hh[a];
    ushort_t h = f2b(v);
    whh_hi[a] = h;
    whh_lo[a] = f2b(v - b2f(h));
  }
  int m = a - 786432;
  if (m >= 0 && m < 147456) {
    int g = m / 96, f = m - g * 96;
    float v = (f < 80) ? w_ih[g * 592 + 512 + f] : 0.f;
    ushort_t h = f2b(v);
    wmel_hi[m] = h;
    wmel_lo[m] = f2b(v - b2f(h));
  }
  int j = m - 147456;
  if (j >= 0 && j < 262144) fc1wb[j] = f2b(fc1w[j]);
  int k = j - 262144;
  if (k >= 0 && k < 262144) fc2wb[k] = f2b(fc2w[k]);
  int c = k - 262144;
  if (c >= 0 && c < 131072) {
    __hip_atomic_store(&h_ring[c], SENT, __ATOMIC_RELAXED, __HIP_MEMORY_SCOPE_AGENT);
  }
}

// ---------------- upsample: repeat+box-filter cascade, one block per (b,f) --
__global__ void upsample_kernel(const float* __restrict__ mels,
                                const float* __restrict__ k0,
                                const float* __restrict__ k1,
                                const float* __restrict__ k2,
                                float* __restrict__ mels_upT) {
  __shared__ float s0[16];
  __shared__ float s1[80];
  __shared__ float s2[400];
  int bf = blockIdx.x;
  int b = bf / 80, f = bf - b * 80;
  int tid = threadIdx.x;  // 128
  float c0 = k0[0], c1 = k1[0], c2 = k2[0];
  if (tid < 16) s0[tid] = mels[(b * 80 + f) * 16 + tid];
  __syncthreads();
  if (tid < 80) {
    float a = 0.f;
    #pragma unroll
    for (int d = -5; d <= 5; ++d) {
      int w = tid + d;
      if (w >= 0 && w < 80) a += s0[w / 5];
    }
    s1[tid] = a * c0;
  }
  __syncthreads();
  for (int w = tid; w < 400; w += 128) {
    float a = 0.f;
    #pragma unroll
    for (int d = -5; d <= 5; ++d) {
      int u = w + d;
      if (u >= 0 && u < 400) a += s1[u / 5];
    }
    s2[w] = a * c1;
  }
  __syncthreads();
  for (int t = tid; t < T_SEQ; t += 128) {
    int wb = 550 + t;
    float a = 0.f;
    #pragma unroll
    for (int d = -11; d <= 11; ++d) a += s2[(wb + d) / 11];
    mels_upT[t * 1280 + b * 80 + f] = a * c2;
  }
}

// ---------------- persistent GRU, pipelined MFMA edition --------------------
// 32 blocks x 512 threads. Block owns h dims [16*blk,16*blk+16) for ALL 16
// batches. Per step: W_hh gate pre-activations = 16x48x512 GEMM (bf16x3 split,
// ~fp32 accurate; verified round 5). All x-side work pipelined OFF the
// critical path:
//   - mel[t+1]: global-load in phase A (hides under poll), split+LDS-write in
//     phase C (double-buffered M), MFMA'd by waves 6-7 in phase B of t+1.
//   - emb: x[t+2] loaded at t; w_ihT rows for t+1 gathered at t via x[t+1]
//     (already in reg -> no dependent stall); consumed at t+1.
// h-staging remapped conflict-free: lane pc handles dword pc+32*jj (global
// 256B-coalesced, LDS banks 0..31 distinct).
// Ring protocol identical to the twice-verified round-5 kernel.
__global__ __launch_bounds__(512) void gru_kernel(
    const int* __restrict__ x,
    const float* __restrict__ mels_upT,   // [t][16][80]
    const float* __restrict__ b_ih,
    const float* __restrict__ b_hh,
    const ushort_t* __restrict__ w_ihT,   // [512][1536] bf16
    const ushort_t* __restrict__ whh_hi,  // [1536][512] bf16
    const ushort_t* __restrict__ whh_lo,
    const ushort_t* __restrict__ wmel_hi, // [1536][96] bf16
    const ushort_t* __restrict__ wmel_lo,
    uint32_t* __restrict__ h_ring,        // [16][16][512] u32 (hi|lo<<16)
    ushort_t* __restrict__ h_seq)         // [16][3300][512] bf16
{
  int blk = blockIdx.x;        // 0..31
  int tid = threadIdx.x;
  int lane = tid & 63, wv = tid >> 6;
  int lm = lane & 15, lq = lane >> 4;
  int pb = tid >> 5, pc = tid & 31;       // poll/stage: batch row, dword lane
  int gb = tid >> 4, gd = tid & 15;       // gate mapping (tid<256)
  int mu = tid - 256;                     // mel-aux index (0..159 active)

  __shared__ __align__(16) ushort_t Hhi[16][520];
  __shared__ __align__(16) ushort_t Hlo[16][520];
  __shared__ __align__(16) ushort_t Mhi[2][16][104];
  __shared__ __align__(16) ushort_t Mlo[2][16][104];
  __shared__ float Cred[9][16][17];       // row pad 17: spreads write banks

  // zero mel K-pads (cols 80..103, both buffers) once
  for (int idx = tid; idx < 2 * 16 * 24; idx += 512) {
    int buf = idx / 384, rem = idx - buf * 384;
    int b = rem / 24, f = 80 + (rem - b * 24);
    Mhi[buf][b][f] = 0; Mlo[buf][b][f] = 0;
  }

  // ---- resident W fragments (layouts verified round 5) ----
  int nt = wv >> 1, kh = wv & 1;
  short8 wbh[8], wbl[8];
  if (wv < 6) {
    int row = nt * 512 + blk * 16 + lm;
    #pragma unroll
    for (int k8 = 0; k8 < 8; ++k8) {
      int kt = kh * 8 + k8;
      wbh[k8] = *(const short8*)(whh_hi + (size_t)row * 512 + kt * 32 + lq * 8);
      wbl[k8] = *(const short8*)(whh_lo + (size_t)row * 512 + kt * 32 + lq * 8);
    }
  }
  short8 wmh[2][3], wml[2][3];
  if (wv >= 6) {
    #pragma unroll
    for (int u = 0; u < 2; ++u) {
      int nt2 = (wv == 6) ? u : 2;
      int row = nt2 * 512 + blk * 16 + lm;
      #pragma unroll
      for (int kt = 0; kt < 3; ++kt) {
        wmh[u][kt] = *(const short8*)(wmel_hi + (size_t)row * 96 + kt * 32 + lq * 8);
        wml[u][kt] = *(const short8*)(wmel_lo + (size_t)row * 96 + kt * 32 + lq * 8);
      }
    }
  }
  // ---- gate constants + emb pipeline regs ----
  float h_prev = 0.f, bsr = 0.f, bsz = 0.f, bihn_ = 0.f, bhhn_ = 0.f;
  float e_r0 = 0.f, e_z0 = 0.f, e_n0 = 0.f;   // emb for current step
  float e_r1 = 0.f, e_z1 = 0.f, e_n1 = 0.f;   // emb for next step (loading)
  int xv1 = 0, xv2 = 0;                        // x[t+1], x[t+2] pipeline
  if (tid < 256) {
    int gr = blk * 16 + gd;
    bsr = b_ih[gr] + b_hh[gr];
    bsz = b_ih[512 + gr] + b_hh[512 + gr];
    bihn_ = b_ih[1024 + gr];
    bhhn_ = b_hh[1024 + gr];
    int x0 = x[gb * T_SEQ];
    const ushort_t* er = w_ihT + (size_t)x0 * 1536 + blk * 16 + gd;
    e_r0 = b2f(er[0]); e_z0 = b2f(er[512]); e_n0 = b2f(er[1024]);
    xv1 = x[gb * T_SEQ + (T_SEQ > 1 ? 1 : 0)];
  }
  // ---- prologue: stage mel[0] into M[0] ----
  if (mu >= 0 && mu < 160) {
    const float* mp = mels_upT + mu * 8;
    f32x4 pa = *(const f32x4*)mp, pb4 = *(const f32x4*)(mp + 4);
    short8 hv, lv;
    #pragma unroll
    for (int e = 0; e < 4; ++e) {
      ushort_t h0 = f2b(pa[e]);
      hv[e] = (short)h0; lv[e] = (short)f2b(pa[e] - b2f(h0));
      ushort_t h1 = f2b(pb4[e]);
      hv[4 + e] = (short)h1; lv[4 + e] = (short)f2b(pb4[e] - b2f(h1));
    }
    int mbb = mu / 10, mf = (mu - mbb * 10) * 8;
    *(short8*)&Mhi[0][mbb][mf] = hv;
    *(short8*)&Mlo[0][mbb][mf] = lv;
  }
  __syncthreads();

  int cur = 0;
  for (int t = 0; t < T_SEQ; ++t) {
    int rslot = (t - 1) & 15, wslot = t & 15, aslot = (t + 8) & 15;
    int t1 = (t + 1 < T_SEQ) ? t + 1 : t;
    // ================= phase A: mel[t+1] load + poll h_{t-1} =================
    f32x4 ma = {0.f, 0.f, 0.f, 0.f}, mb4 = {0.f, 0.f, 0.f, 0.f};
    if (mu >= 0 && mu < 160) {
      const float* mp = mels_upT + (size_t)t1 * 1280 + mu * 8;
      ma = *(const f32x4*)mp;
      mb4 = *(const f32x4*)(mp + 4);
    }
    u64 q[8];
    #pragma unroll
    for (int jj = 0; jj < 8; ++jj) q[jj] = 0;
    if (t > 0) {
      const u64* src = (const u64*)&h_ring[((rslot * 16 + pb) << 9)];
      // escape hatch: exhaustion leaves NaN sentinels (visible absmax failure)
      for (int spin = 0; spin < 4096; ++spin) {
        bool ok = true;
        #pragma unroll
        for (int jj = 0; jj < 8; ++jj) {
          q[jj] = __hip_atomic_load(src + pc + 32 * jj, __ATOMIC_RELAXED,
                                    __HIP_MEMORY_SCOPE_AGENT);
          ok = ok && (((uint32_t)q[jj]) != SENT) && (((uint32_t)(q[jj] >> 32)) != SENT);
        }
        if (ok) break;
      }
    }
    {  // unpack: lane pc writes dword pc+32*jj -> banks 0..31 distinct
      uint32_t* hrow = (uint32_t*)&Hhi[pb][0];
      uint32_t* lrow = (uint32_t*)&Hlo[pb][0];
      #pragma unroll
      for (int jj = 0; jj < 8; ++jj) {
        uint32_t w0 = (uint32_t)q[jj], w1 = (uint32_t)(q[jj] >> 32);
        hrow[pc + 32 * jj] = (w0 & 0xFFFFu) | (w1 << 16);
        lrow[pc + 32 * jj] = (w0 >> 16) | (w1 & 0xFFFF0000u);
      }
    }
    __syncthreads();

    // ================= phase B: MFMA + emb/x prefetch =================
    if (tid < 256) {
      int t2 = (t + 2 < T_SEQ) ? t + 2 : t;
      xv2 = x[gb * T_SEQ + t2];
      const ushort_t* er = w_ihT + (size_t)xv1 * 1536 + blk * 16 + gd;
      e_r1 = b2f(er[0]); e_z1 = b2f(er[512]); e_n1 = b2f(er[1024]);
    }
    if (wv < 6) {
      short8 ah[8], al[8];
      #pragma unroll
      for (int k8 = 0; k8 < 8; ++k8) {
        int kk = (kh * 8 + k8) * 32 + lq * 8;
        ah[k8] = *(const short8*)&Hhi[lm][kk];
        al[k8] = *(const short8*)&Hlo[lm][kk];
      }
      f32x4 ce = {0.f, 0.f, 0.f, 0.f}, co = {0.f, 0.f, 0.f, 0.f};
      #pragma unroll
      for (int k8 = 0; k8 < 8; ++k8) {
        ce = __builtin_amdgcn_mfma_f32_16x16x32_bf16(ah[k8], wbh[k8], ce, 0, 0, 0);
        co = __builtin_amdgcn_mfma_f32_16x16x32_bf16(al[k8], wbh[k8], co, 0, 0, 0);
        ce = __builtin_amdgcn_mfma_f32_16x16x32_bf16(ah[k8], wbl[k8], ce, 0, 0, 0);
      }
      #pragma unroll
      for (int r = 0; r < 4; ++r) Cred[wv][lq * 4 + r][lm] = ce[r] + co[r];
    } else {
      short8 amh[3], aml[3];
      #pragma unroll
      for (int kt = 0; kt < 3; ++kt) {
        amh[kt] = *(const short8*)&Mhi[cur][lm][kt * 32 + lq * 8];
        aml[kt] = *(const short8*)&Mlo[cur][lm][kt * 32 + lq * 8];
      }
      #pragma unroll
      for (int u = 0; u < 2; ++u) {
        if (!(wv == 7 && u == 1)) {
          f32x4 cm = {0.f, 0.f, 0.f, 0.f};
          #pragma unroll
          for (int kt = 0; kt < 3; ++kt) {
            cm = __builtin_amdgcn_mfma_f32_16x16x32_bf16(amh[kt], wmh[u][kt], cm, 0, 0, 0);
            cm = __builtin_amdgcn_mfma_f32_16x16x32_bf16(aml[kt], wmh[u][kt], cm, 0, 0, 0);
            cm = __builtin_amdgcn_mfma_f32_16x16x32_bf16(amh[kt], wml[u][kt], cm, 0, 0, 0);
          }
          int cslot = (wv == 6) ? (6 + u) : 8;
          #pragma unroll
          for (int r = 0; r < 4; ++r) Cred[cslot][lq * 4 + r][lm] = cm[r];
        }
      }
    }
    __syncthreads();

    // ================= phase C: gates+publish | mel split+write =============
    if (tid < 256) {
      float hr = Cred[0][gb][gd] + Cred[1][gb][gd];
      float hz = Cred[2][gb][gd] + Cred[3][gb][gd];
      float hn = Cred[4][gb][gd] + Cred[5][gb][gd];
      float mr = Cred[6][gb][gd], mz = Cred[7][gb][gd], mn = Cred[8][gb][gd];
      float ar = e_r0 + mr + hr + bsr;
      float az = e_z0 + mz + hz + bsz;
      float rg = 1.f / (1.f + __expf(-ar));
      float zg = 1.f / (1.f + __expf(-az));
      float xn = e_n0 + mn + bihn_;
      float hns = hn + bhhn_;
      float na = xn + rg * hns;
      float e2 = __expf(2.f * na);
      float ng = 1.f - 2.f / (e2 + 1.f);   // tanh
      float h = (1.f - zg) * ng + zg * h_prev;
      h_prev = h;
      ushort_t hib = f2b(h);
      ushort_t lob = f2b(h - b2f(hib));
      uint32_t pk = (uint32_t)hib | ((uint32_t)lob << 16);
      __hip_atomic_store(&h_ring[((wslot * 16 + gb) << 9) + blk * 16 + gd], pk,
                         __ATOMIC_RELAXED, __HIP_MEMORY_SCOPE_AGENT);
      __hip_atomic_store(&h_ring[((aslot * 16 + gb) << 9) + blk * 16 + gd], SENT,
                         __ATOMIC_RELAXED, __HIP_MEMORY_SCOPE_AGENT);
      h_seq[(size_t)(gb * T_SEQ + t) * 512 + blk * 16 + gd] = hib;
    } else if (mu < 160) {
      short8 hv, lv;
      #pragma unroll
      for (int e = 0; e < 4; ++e) {
        ushort_t h0 = f2b(ma[e]);
        hv[e] = (short)h0; lv[e] = (short)f2b(ma[e] - b2f(h0));
        ushort_t h1 = f2b(mb4[e]);
        hv[4 + e] = (short)h1; lv[4 + e] = (short)f2b(mb4[e] - b2f(h1));
      }
      int mbb = mu / 10, mf = (mu - mbb * 10) * 8;
      *(short8*)&Mhi[cur ^ 1][mbb][mf] = hv;
      *(short8*)&Mlo[cur ^ 1][mbb][mf] = lv;
    }
    __syncthreads();
    cur ^= 1;
    if (tid < 256) {
      e_r0 = e_r1; e_z0 = e_z1; e_n0 = e_n1;
      xv1 = xv2;
    }
  }
}

// ---------------- fused head: relu(h*fc1^T+b1)*fc2^T+b2 via bf16 MFMA -------
__global__ __launch_bounds__(512) void head_kernel(
    const ushort_t* __restrict__ h_seq,
    const ushort_t* __restrict__ fc1w,   // [n][k] bf16
    const ushort_t* __restrict__ fc2w,   // [n][k] bf16
    const float* __restrict__ fc1b,
    const float* __restrict__ fc2b,
    float* __restrict__ out) {
  __shared__ __align__(16) ushort_t h1[64 * 512];
  int blk = blockIdx.x;          // 825 blocks, 64 rows each
  int tid = threadIdx.x;
  int w = tid >> 6, l = tid & 63;
  int lm = l & 15, lq = l >> 4;
  int mt = w & 3;
  int nb = (w >> 2) * 256;
  int m0 = blk * 64;

  f32x4 acc[16];
  #pragma unroll
  for (int i = 0; i < 16; ++i) acc[i] = (f32x4){0.f, 0.f, 0.f, 0.f};
  const ushort_t* arow = h_seq + (size_t)(m0 + mt * 16 + lm) * 512;
  for (int kt = 0; kt < 16; ++kt) {
    short8 a = *(const short8*)(arow + kt * 32 + lq * 8);
    #pragma unroll
    for (int nt = 0; nt < 16; ++nt) {
      short8 bb = *(const short8*)(fc1w + (size_t)(nb + nt * 16 + lm) * 512 + kt * 32 + lq * 8);
      acc[nt] = __builtin_amdgcn_mfma_f32_16x16x32_bf16(a, bb, acc[nt], 0, 0, 0);
    }
  }
  #pragma unroll
  for (int nt = 0; nt < 16; ++nt) {
    int n = nb + nt * 16 + lm;
    float bias = fc1b[n];
    #pragma unroll
    for (int r = 0; r < 4; ++r) {
      int m = mt * 16 + lq * 4 + r;
      float vv = acc[nt][r] + bias;
      vv = fmaxf(vv, 0.f);
      h1[m * 512 + n] = f2b(vv);
    }
  }
  __syncthreads();
  f32x4 acc2[16];
  #pragma unroll
  for (int i = 0; i < 16; ++i) acc2[i] = (f32x4){0.f, 0.f, 0.f, 0.f};
  for (int kt = 0; kt < 16; ++kt) {
    short8 a = *(const short8*)&h1[(mt * 16 + lm) * 512 + kt * 32 + lq * 8];
    #pragma unroll
    for (int nt = 0; nt < 16; ++nt) {
      short8 bb = *(const short8*)(fc2w + (size_t)(nb + nt * 16 + lm) * 512 + kt * 32 + lq * 8);
      acc2[nt] = __builtin_amdgcn_mfma_f32_16x16x32_bf16(a, bb, acc2[nt], 0, 0, 0);
    }
  }
  #pragma unroll
  for (int nt = 0; nt < 16; ++nt) {
    int n = nb + nt * 16 + lm;
    float bias = fc2b[n];
    #pragma unroll
    for (int r = 0; r < 4; ++r) {
      int m = mt * 16 + lq * 4 + r;
      out[(size_t)(m0 + m) * 512 + n] = acc2[nt][r] + bias;
    }
  }
}

// ---------------- launch -----------------------------------------------------
extern "C" void kernel_launch(void* const* d_in, const int* in_sizes, int n_in,
                              void* d_out, int out_size, void* d_ws, size_t ws_size,
                              hipStream_t stream) {
  (void)in_sizes; (void)n_in; (void)out_size; (void)ws_size;
  const int*   x    = (const int*)d_in[0];
  const float* mels = (const float*)d_in[1];
  const float* k0   = (const float*)d_in[2];
  const float* k1   = (const float*)d_in[3];
  const float* k2   = (const float*)d_in[4];
  const float* w_ih = (const float*)d_in[5];
  const float* w_hh = (const float*)d_in[6];
  const float* b_ih = (const float*)d_in[7];
  const float* b_hh = (const float*)d_in[8];
  const float* fc1w = (const float*)d_in[9];
  const float* fc1b = (const float*)d_in[10];
  const float* fc2w = (const float*)d_in[11];
  const float* fc2b = (const float*)d_in[12];

  char* ws = (char*)d_ws;   // footprint identical to the proven baseline
  float*    mels_upT = (float*)(ws + 0);           // 3300*1280*4   = 16,896,000
  ushort_t* h_seq    = (ushort_t*)(ws + 16896000); // 16*3300*512*2 = 54,067,200
  ushort_t* w_ihT    = (ushort_t*)(ws + 70963200); // 512*1536*2    =  1,572,864
  ushort_t* fc1wb    = (ushort_t*)(ws + 72536064); // 512*512*2     =    524,288
  ushort_t* fc2wb    = (ushort_t*)(ws + 73060352); // 512*512*2     =    524,288
  uint32_t* h_ring   = (uint32_t*)(ws + 73584640); // 16*16*512*4   =    524,288

  // Split-weight scratch in the TAIL of d_out (written by prep every run,
  // read only by gru, overwritten by head afterwards).
  char* ob = (char*)d_out;
  ushort_t* whh_hi  = (ushort_t*)(ob + OUT_BYTES - 3735552); // 1,572,864
  ushort_t* whh_lo  = (ushort_t*)(ob + OUT_BYTES - 2162688); // 1,572,864
  ushort_t* wmel_hi = (ushort_t*)(ob + OUT_BYTES -  589824); //   294,912
  ushort_t* wmel_lo = (ushort_t*)(ob + OUT_BYTES -  294912); //   294,912

  prep_kernel<<<9280, 256, 0, stream>>>(w_ih, w_hh, fc1w, fc2w, w_ihT,
                                        whh_hi, whh_lo, wmel_hi, wmel_lo,
                                        fc1wb, fc2wb, h_ring);
  upsample_kernel<<<1280, 128, 0, stream>>>(mels, k0, k1, k2, mels_upT);
  gru_kernel<<<32, 512, 0, stream>>>(x, mels_upT, b_ih, b_hh, w_ihT,
                                     whh_hi, whh_lo, wmel_hi, wmel_lo,
                                     h_ring, h_seq);
  head_kernel<<<825, 512, 0, stream>>>(h_seq, fc1wb, fc2wb, fc1b, fc2b, (float*)d_out);
}

// Round 7
// 8123.035 us; speedup vs baseline: 1.3661x; 1.0485x over previous
//
#include <hip/hip_runtime.h>
#include <stdint.h>

typedef unsigned short ushort_t;
typedef unsigned long long u64;
typedef __attribute__((ext_vector_type(8))) short short8;
typedef __attribute__((ext_vector_type(4))) float f32x4;

#define T_SEQ 3300
#define SENT 0x7FC00001u
#define SENTPAIR 0x7FC000017FC00001ull

__device__ __forceinline__ ushort_t f2b(float f) {
  uint32_t u = __float_as_uint(f);
  u = (u + 0x7fffu + ((u >> 16) & 1u)) >> 16;
  return (ushort_t)u;
}
__device__ __forceinline__ float b2f(ushort_t b) {
  return __uint_as_float(((uint32_t)b) << 16);
}

// ---------------- prep: weight transpose/convert + ring sentinel init -------
__global__ void prep_kernel(const float* __restrict__ w_ih,
                            const float* __restrict__ fc1w,
                            const float* __restrict__ fc2w,
                            ushort_t* __restrict__ w_ihT,
                            ushort_t* __restrict__ fc1wb,
                            ushort_t* __restrict__ fc2wb,
                            uint32_t* __restrict__ h_ring) {
  int i = blockIdx.x * 256 + threadIdx.x;
  if (i < 512 * 1536) {            // w_ihT[d][g] = w_ih[g][d], d<512 (one-hot rows)
    int d = i / 1536, g = i - d * 1536;
    w_ihT[i] = f2b(w_ih[g * 592 + d]);
  }
  int j = i - 512 * 1536;
  if (j >= 0 && j < 262144) fc1wb[j] = f2b(fc1w[j]);
  int k = j - 262144;
  if (k >= 0 && k < 262144) fc2wb[k] = f2b(fc2w[k]);
  int c = k - 262144;
  if (c >= 0 && c < 131072) {
    // sentinel must be visible at the coherence point (gru reads bypass L2),
    // so write it with a cache-bypassing relaxed agent atomic store.
    __hip_atomic_store(&h_ring[c], SENT, __ATOMIC_RELAXED, __HIP_MEMORY_SCOPE_AGENT);
  }
}

// ---------------- upsample: repeat+box-filter cascade, one block per (b,f) --
__global__ void upsample_kernel(const float* __restrict__ mels,
                                const float* __restrict__ k0,
                                const float* __restrict__ k1,
                                const float* __restrict__ k2,
                                float* __restrict__ mels_up) {
  __shared__ float s0[16];
  __shared__ float s1[80];
  __shared__ float s2[400];
  int bf = blockIdx.x;
  int b = bf / 80, f = bf - b * 80;
  int tid = threadIdx.x;  // 128
  float c0 = k0[0], c1 = k1[0], c2 = k2[0];
  if (tid < 16) s0[tid] = mels[(b * 80 + f) * 16 + tid];
  __syncthreads();
  if (tid < 80) {
    float a = 0.f;
    #pragma unroll
    for (int d = -5; d <= 5; ++d) {
      int w = tid + d;
      if (w >= 0 && w < 80) a += s0[w / 5];
    }
    s1[tid] = a * c0;
  }
  __syncthreads();
  for (int w = tid; w < 400; w += 128) {
    float a = 0.f;
    #pragma unroll
    for (int d = -5; d <= 5; ++d) {
      int u = w + d;
      if (u >= 0 && u < 400) a += s1[u / 5];
    }
    s2[w] = a * c1;
  }
  __syncthreads();
  for (int t = tid; t < T_SEQ; t += 128) {
    int wb = 550 + t;   // wb+d in [539,3860] -> /11 < 400: no bounds needed
    float a = 0.f;
    #pragma unroll
    for (int d = -11; d <= 11; ++d) a += s2[(wb + d) / 11];
    mels_up[(b * 80 + f) * T_SEQ + t] = a * c2;
  }
}

// ---- 32-lane sum: DPP row_shr cascade (16) + shfl_xor 16. Valid on lane cc==15 (and 31).
__device__ __forceinline__ float red32(float x) {
  x += __uint_as_float((uint32_t)__builtin_amdgcn_update_dpp(0, (int)__float_as_uint(x), 0x111, 0xf, 0xf, true));
  x += __uint_as_float((uint32_t)__builtin_amdgcn_update_dpp(0, (int)__float_as_uint(x), 0x112, 0xf, 0xf, true));
  x += __uint_as_float((uint32_t)__builtin_amdgcn_update_dpp(0, (int)__float_as_uint(x), 0x114, 0xf, 0xf, true));
  x += __uint_as_float((uint32_t)__builtin_amdgcn_update_dpp(0, (int)__float_as_uint(x), 0x118, 0xf, 0xf, true));
  x += __shfl_xor(x, 16, 64);
  return x;
}

// ---------------- persistent GRU --------------------------------------------
// 256 blocks x 512 threads. Group = batch b (16 blocks); block j owns h dims [32j,32j+32).
// Cross-block h exchange: 16-slot ring h_ring[slot][b][512] (fp32), written/read with
// RELAXED AGENT atomics (cache-bypassing; protocol verified at 6.77ms baseline).
// Readiness = data != NaN-sentinel; slot re-armed to sentinel 8 steps ahead.
// THIS VERSION: LDS double-buffered (v/embs ping-pong) -> ONE barrier per step.
// The end-of-step __syncthreads (whose implicit vmcnt(0) made every wave drain
// its agent-scope publish stores, ~700cy, serially) is gone; the drain now
// overlaps the next step's poll. Safety: reads of buf p=t&1 happen after
// barrier t; the next writes to buf p occur in iter t+2 before barrier t+2,
// and any thread there has passed barrier t+1, which requires all threads to
// have finished iter t's reads.
__global__ __launch_bounds__(512) void gru_kernel(
    const int* __restrict__ x,
    const float* __restrict__ mels_up,
    const float* __restrict__ w_ih,
    const float* __restrict__ w_hh,
    const float* __restrict__ b_ih,
    const float* __restrict__ b_hh,
    const ushort_t* __restrict__ w_ihT,
    uint32_t* __restrict__ h_ring,  // [16][16][512] fp32 bits
    ushort_t* __restrict__ h_seq)   // [16][3300][512] bf16
{
  int blk = blockIdx.x;
  int xcd = blk & 7, slot = blk >> 3;
  int b = (xcd << 1) | (slot >> 4);   // XCD-spread heuristic only; correctness agnostic
  int j = slot & 15;
  int tid = threadIdx.x;
  int cc = tid & 31, rr = tid >> 5;

  __shared__ __align__(16) float v[2][640];    // [0,512)=h, [512,592)=mel, rest 0
  __shared__ float embs[2][96];

  if (tid < 48) { v[0][592 + tid] = 0.f; v[1][592 + tid] = 0.f; }

  // ---- load resident weights ----
  float w[6][20];
  float wmel[2][3];
  float bsum[4], bihn[2], bhhn[2];
  #pragma unroll
  for (int q = 0; q < 6; ++q) {
    int gate = q >> 1, kk = q & 1;
    int g = gate * 512 + j * 32 + rr * 2 + kk;
    #pragma unroll
    for (int cl = 0; cl < 20; ++cl) {
      int col = cc * 20 + cl;
      float wv = 0.f;
      if (col < 512) wv = w_hh[g * 512 + col];
      else if (col < 592 && gate < 2) wv = w_ih[g * 592 + col]; // mel weights (r,z only)
      w[q][cl] = wv;
    }
  }
  #pragma unroll
  for (int kk = 0; kk < 2; ++kk) {
    int g = 1024 + j * 32 + rr * 2 + kk;
    #pragma unroll
    for (int ii = 0; ii < 3; ++ii) {
      int fidx = cc * 3 + ii;
      wmel[kk][ii] = (fidx < 80) ? w_ih[g * 592 + 512 + fidx] : 0.f;
    }
    bihn[kk] = b_ih[g];
    bhhn[kk] = b_hh[g];
  }
  #pragma unroll
  for (int q = 0; q < 4; ++q) {
    int gate = q >> 1, kk = q & 1;
    int g = gate * 512 + j * 32 + rr * 2 + kk;
    bsum[q] = b_ih[g] + b_hh[g];
  }

  for (int t = 0; t < T_SEQ; ++t) {
    int p = t & 1;
    // ---- prefetch (independent of h; plain cached loads) ----
    float melv = 0.f;
    if (tid < 80) melv = mels_up[(b * 80 + tid) * T_SEQ + t];
    float embv = 0.f;
    if (tid < 96) {
      int xv = x[b * T_SEQ + t];
      int gate = tid >> 5, kl = tid & 31;
      embv = b2f(w_ihT[xv * 1536 + gate * 512 + j * 32 + kl]);
    }
    // ---- poll h_{t-1} directly on data (sentinel = not ready) ----
    u64 q0 = 0, q1 = 0;
    if (t > 0 && tid < 128) {
      int rslot = (t - 1) & 15;
      const u64* src = (const u64*)&h_ring[((rslot * 16 + b) * 512) + tid * 4];
      // escape hatch: legit waits are <2 iters; exhaustion leaves NaN sentinels
      // in the output (visible absmax failure) instead of a hung container.
      for (int spin = 0; spin < 8192; ++spin) {
        q0 = __hip_atomic_load(src,     __ATOMIC_RELAXED, __HIP_MEMORY_SCOPE_AGENT);
        q1 = __hip_atomic_load(src + 1, __ATOMIC_RELAXED, __HIP_MEMORY_SCOPE_AGENT);
        if (((uint32_t)q0) != SENT && ((uint32_t)(q0 >> 32)) != SENT &&
            ((uint32_t)q1) != SENT && ((uint32_t)(q1 >> 32)) != SENT) break;
      }
    }
    // ---- stage v = [h | mel] and emb into LDS buffer p ----
    if (tid < 128) {
      ((u64*)v[p])[tid * 2]     = q0;   // t==0 -> zeros
      ((u64*)v[p])[tid * 2 + 1] = q1;
    }
    if (tid < 80) v[p][512 + tid] = melv;
    if (tid < 96) embs[p][tid] = embv;
    __syncthreads();   // the ONLY barrier per step

    // ---- matvec: acc[q] = sum_cols v[col]*W[row(q)][col] ----
    float hv20[20];
    #pragma unroll
    for (int s = 0; s < 5; ++s) {
      f32x4 t4 = *(const f32x4*)&v[p][cc * 20 + s * 4];
      hv20[s * 4 + 0] = t4[0]; hv20[s * 4 + 1] = t4[1];
      hv20[s * 4 + 2] = t4[2]; hv20[s * 4 + 3] = t4[3];
    }
    float a0 = 0.f, a1 = 0.f, a2 = 0.f, a3 = 0.f, a4 = 0.f, a5 = 0.f;
    #pragma unroll
    for (int cl = 0; cl < 20; ++cl) {
      float hvv = hv20[cl];
      a0 += hvv * w[0][cl]; a1 += hvv * w[1][cl];
      a2 += hvv * w[2][cl]; a3 += hvv * w[3][cl];
      a4 += hvv * w[4][cl]; a5 += hvv * w[5][cl];
    }
    float am0 = 0.f, am1 = 0.f;   // n-gate x-side mel part (kept separate from h-side)
    #pragma unroll
    for (int ii = 0; ii < 3; ++ii) {
      float mv = v[p][512 + cc * 3 + ii];
      am0 += mv * wmel[0][ii]; am1 += mv * wmel[1][ii];
    }
    float r0 = red32(a0), r1 = red32(a1), r2 = red32(a2);
    float r3 = red32(a3), r4 = red32(a4), r5 = red32(a5);
    float rm0 = red32(am0), rm1 = red32(am1);

    if (cc == 15) {
      float hn2[2];
      #pragma unroll
      for (int kk = 0; kk < 2; ++kk) {
        float sr  = kk ? r1 : r0;
        float sz  = kk ? r3 : r2;
        float sn  = kk ? r5 : r4;
        float smn = kk ? rm1 : rm0;
        int k = rr * 2 + kk;
        float ar = embs[p][k] + sr + bsum[0 + kk];
        float az = embs[p][32 + k] + sz + bsum[2 + kk];
        float rg = 1.f / (1.f + __expf(-ar));
        float zg = 1.f / (1.f + __expf(-az));
        float xn = embs[p][64 + k] + smn + bihn[kk];
        float hn = sn + bhhn[kk];
        float na = xn + rg * hn;
        float e2 = __expf(2.f * na);
        float ng = 1.f - 2.f / (e2 + 1.f);   // tanh
        float hp = v[p][j * 32 + k];
        hn2[kk] = (1.f - zg) * ng + zg * hp;
      }
      // publish h_t: cache-bypassing relaxed agent store (no cache maintenance)
      int wslot = t & 15;
      u64 pk = ((u64)__float_as_uint(hn2[1]) << 32) | (u64)__float_as_uint(hn2[0]);
      u64* dst = (u64*)&h_ring[((wslot * 16 + b) * 512) + j * 32 + rr * 2];
      __hip_atomic_store(dst, pk, __ATOMIC_RELAXED, __HIP_MEMORY_SCOPE_AGENT);
      // re-arm slot t+8 (next written at t+8, last read at t-7: safe margin;
      // same-thread same-address order preserved by the per-step barrier's
      // implicit vmcnt drain: 8 barriers separate any same-slot store pair)
      int aslot = (t + 8) & 15;
      u64* adst = (u64*)&h_ring[((aslot * 16 + b) * 512) + j * 32 + rr * 2];
      __hip_atomic_store(adst, SENTPAIR, __ATOMIC_RELAXED, __HIP_MEMORY_SCOPE_AGENT);
      // h_seq for the head (plain cached store; kernel boundary makes it visible)
      uint32_t hb = (uint32_t)f2b(hn2[0]) | ((uint32_t)f2b(hn2[1]) << 16);
      *(uint32_t*)&h_seq[(size_t)(b * T_SEQ + t) * 512 + j * 32 + rr * 2] = hb;
    }
    // no end-of-step barrier: next iteration writes buffer p^1
  }
}

// ---------------- fused head: relu(h*fc1^T+b1)*fc2^T+b2 via bf16 MFMA -------
__global__ __launch_bounds__(512) void head_kernel(
    const ushort_t* __restrict__ h_seq,
    const ushort_t* __restrict__ fc1w,   // [n][k] bf16
    const ushort_t* __restrict__ fc2w,   // [n][k] bf16
    const float* __restrict__ fc1b,
    const float* __restrict__ fc2b,
    float* __restrict__ out) {
  __shared__ __align__(16) ushort_t h1[64 * 512];
  int blk = blockIdx.x;          // 825 blocks, 64 rows each
  int tid = threadIdx.x;
  int w = tid >> 6, l = tid & 63;
  int lm = l & 15, lq = l >> 4;
  int mt = w & 3;                // m-tile within the 64-row block
  int nb = (w >> 2) * 256;       // this wave's n-range
  int m0 = blk * 64;

  // stage 1: h1 = relu(h*fc1^T + b1)
  f32x4 acc[16];
  #pragma unroll
  for (int i = 0; i < 16; ++i) acc[i] = (f32x4){0.f, 0.f, 0.f, 0.f};
  const ushort_t* arow = h_seq + (size_t)(m0 + mt * 16 + lm) * 512;
  for (int kt = 0; kt < 16; ++kt) {
    short8 a = *(const short8*)(arow + kt * 32 + lq * 8);
    #pragma unroll
    for (int nt = 0; nt < 16; ++nt) {
      short8 bb = *(const short8*)(fc1w + (size_t)(nb + nt * 16 + lm) * 512 + kt * 32 + lq * 8);
      acc[nt] = __builtin_amdgcn_mfma_f32_16x16x32_bf16(a, bb, acc[nt], 0, 0, 0);
    }
  }
  #pragma unroll
  for (int nt = 0; nt < 16; ++nt) {
    int n = nb + nt * 16 + lm;
    float bias = fc1b[n];
    #pragma unroll
    for (int r = 0; r < 4; ++r) {
      int m = mt * 16 + lq * 4 + r;
      float vv = acc[nt][r] + bias;
      vv = fmaxf(vv, 0.f);
      h1[m * 512 + n] = f2b(vv);
    }
  }
  __syncthreads();
  // stage 2: out = h1*fc2^T + b2
  f32x4 acc2[16];
  #pragma unroll
  for (int i = 0; i < 16; ++i) acc2[i] = (f32x4){0.f, 0.f, 0.f, 0.f};
  for (int kt = 0; kt < 16; ++kt) {
    short8 a = *(const short8*)&h1[(mt * 16 + lm) * 512 + kt * 32 + lq * 8];
    #pragma unroll
    for (int nt = 0; nt < 16; ++nt) {
      short8 bb = *(const short8*)(fc2w + (size_t)(nb + nt * 16 + lm) * 512 + kt * 32 + lq * 8);
      acc2[nt] = __builtin_amdgcn_mfma_f32_16x16x32_bf16(a, bb, acc2[nt], 0, 0, 0);
    }
  }
  #pragma unroll
  for (int nt = 0; nt < 16; ++nt) {
    int n = nb + nt * 16 + lm;
    float bias = fc2b[n];
    #pragma unroll
    for (int r = 0; r < 4; ++r) {
      int m = mt * 16 + lq * 4 + r;
      out[(size_t)(m0 + m) * 512 + n] = acc2[nt][r] + bias;
    }
  }
}

// ---------------- launch -----------------------------------------------------
extern "C" void kernel_launch(void* const* d_in, const int* in_sizes, int n_in,
                              void* d_out, int out_size, void* d_ws, size_t ws_size,
                              hipStream_t stream) {
  (void)in_sizes; (void)n_in; (void)out_size; (void)ws_size;
  const int*   x    = (const int*)d_in[0];
  const float* mels = (const float*)d_in[1];
  const float* k0   = (const float*)d_in[2];
  const float* k1   = (const float*)d_in[3];
  const float* k2   = (const float*)d_in[4];
  const float* w_ih = (const float*)d_in[5];
  const float* w_hh = (const float*)d_in[6];
  const float* b_ih = (const float*)d_in[7];
  const float* b_hh = (const float*)d_in[8];
  const float* fc1w = (const float*)d_in[9];
  const float* fc1b = (const float*)d_in[10];
  const float* fc2w = (const float*)d_in[11];
  const float* fc2b = (const float*)d_in[12];

  char* ws = (char*)d_ws;
  float*    mels_up = (float*)(ws + 0);           // 16*80*3300*4  = 16,896,000
  ushort_t* h_seq   = (ushort_t*)(ws + 16896000); // 16*3300*512*2 = 54,067,200
  ushort_t* w_ihT   = (ushort_t*)(ws + 70963200); // 512*1536*2    =  1,572,864
  ushort_t* fc1wb   = (ushort_t*)(ws + 72536064); // 512*512*2     =    524,288
  ushort_t* fc2wb   = (ushort_t*)(ws + 73060352); // 512*512*2     =    524,288
  uint32_t* h_ring  = (uint32_t*)(ws + 73584640); // 16*16*512*4   =    524,288

  prep_kernel<<<5632, 256, 0, stream>>>(w_ih, fc1w, fc2w, w_ihT, fc1wb, fc2wb, h_ring);
  upsample_kernel<<<1280, 128, 0, stream>>>(mels, k0, k1, k2, mels_up);
  gru_kernel<<<256, 512, 0, stream>>>(x, mels_up, w_ih, w_hh, b_ih, b_hh, w_ihT,
                                      h_ring, h_seq);
  head_kernel<<<825, 512, 0, stream>>>(h_seq, fc1wb, fc2wb, fc1b, fc2b, (float*)d_out);
}

// Round 8
// 7209.429 us; speedup vs baseline: 1.5392x; 1.1267x over previous
//
#include <hip/hip_runtime.h>
#include <stdint.h>

typedef unsigned short ushort_t;
typedef unsigned long long u64;
typedef __attribute__((ext_vector_type(8))) short short8;
typedef __attribute__((ext_vector_type(4))) float f32x4;
typedef __attribute__((ext_vector_type(2))) float f32x2;

#define T_SEQ 3300
#define SENT 0x7FC00001u
#define SENTPAIR 0x7FC000017FC00001ull

__device__ __forceinline__ ushort_t f2b(float f) {
  uint32_t u = __float_as_uint(f);
  u = (u + 0x7fffu + ((u >> 16) & 1u)) >> 16;
  return (ushort_t)u;
}
__device__ __forceinline__ float b2f(ushort_t b) {
  return __uint_as_float(((uint32_t)b) << 16);
}

// ---------------- prep: weight transpose/convert + ring sentinel init -------
__global__ void prep_kernel(const float* __restrict__ w_ih,
                            const float* __restrict__ fc1w,
                            const float* __restrict__ fc2w,
                            ushort_t* __restrict__ w_ihT,
                            ushort_t* __restrict__ fc1wb,
                            ushort_t* __restrict__ fc2wb,
                            uint32_t* __restrict__ h_ring) {
  int i = blockIdx.x * 256 + threadIdx.x;
  if (i < 512 * 1536) {            // w_ihT[d][g] = w_ih[g][d], d<512 (one-hot rows)
    int d = i / 1536, g = i - d * 1536;
    w_ihT[i] = f2b(w_ih[g * 592 + d]);
  }
  int j = i - 512 * 1536;
  if (j >= 0 && j < 262144) fc1wb[j] = f2b(fc1w[j]);
  int k = j - 262144;
  if (k >= 0 && k < 262144) fc2wb[k] = f2b(fc2w[k]);
  int c = k - 262144;
  if (c >= 0 && c < 131072) {
    // sentinel must be visible at the coherence point (gru reads bypass L2),
    // so write it with a cache-bypassing relaxed agent atomic store.
    __hip_atomic_store(&h_ring[c], SENT, __ATOMIC_RELAXED, __HIP_MEMORY_SCOPE_AGENT);
  }
}

// ---------------- upsample: repeat+box-filter cascade, one block per (b,f) --
__global__ void upsample_kernel(const float* __restrict__ mels,
                                const float* __restrict__ k0,
                                const float* __restrict__ k1,
                                const float* __restrict__ k2,
                                float* __restrict__ mels_up) {
  __shared__ float s0[16];
  __shared__ float s1[80];
  __shared__ float s2[400];
  int bf = blockIdx.x;
  int b = bf / 80, f = bf - b * 80;
  int tid = threadIdx.x;  // 128
  float c0 = k0[0], c1 = k1[0], c2 = k2[0];
  if (tid < 16) s0[tid] = mels[(b * 80 + f) * 16 + tid];
  __syncthreads();
  if (tid < 80) {
    float a = 0.f;
    #pragma unroll
    for (int d = -5; d <= 5; ++d) {
      int w = tid + d;
      if (w >= 0 && w < 80) a += s0[w / 5];
    }
    s1[tid] = a * c0;
  }
  __syncthreads();
  for (int w = tid; w < 400; w += 128) {
    float a = 0.f;
    #pragma unroll
    for (int d = -5; d <= 5; ++d) {
      int u = w + d;
      if (u >= 0 && u < 400) a += s1[u / 5];
    }
    s2[w] = a * c1;
  }
  __syncthreads();
  for (int t = tid; t < T_SEQ; t += 128) {
    int wb = 550 + t;   // wb+d in [539,3860] -> /11 < 400: no bounds needed
    float a = 0.f;
    #pragma unroll
    for (int d = -11; d <= 11; ++d) a += s2[(wb + d) / 11];
    mels_up[(b * 80 + f) * T_SEQ + t] = a * c2;
  }
}

// ---- 32-lane sum: DPP row_shr cascade (16) + shfl_xor 16. Valid on lane cc==15 (and 31).
__device__ __forceinline__ float red32(float x) {
  x += __uint_as_float((uint32_t)__builtin_amdgcn_update_dpp(0, (int)__float_as_uint(x), 0x111, 0xf, 0xf, true));
  x += __uint_as_float((uint32_t)__builtin_amdgcn_update_dpp(0, (int)__float_as_uint(x), 0x112, 0xf, 0xf, true));
  x += __uint_as_float((uint32_t)__builtin_amdgcn_update_dpp(0, (int)__float_as_uint(x), 0x114, 0xf, 0xf, true));
  x += __uint_as_float((uint32_t)__builtin_amdgcn_update_dpp(0, (int)__float_as_uint(x), 0x118, 0xf, 0xf, true));
  x += __shfl_xor(x, 16, 64);
  return x;
}

// ---------------- persistent GRU --------------------------------------------
// 256 blocks x 512 threads. Group = batch b (16 blocks); block j owns h dims [32j,32j+32).
// Cross-block h exchange: 16-slot ring h_ring[slot][b][512] (fp32), written/read with
// RELAXED AGENT atomics. Structure byte-identical to the verified 6.3ms baseline
// (two __syncthreads per step — every variant tried was slower).
// ONLY change: matvec inner loop uses v_pk_fma_f32 (packed 2xfp32, VOP3P) --
// 120 scalar FMA -> 60 packed + 6 horizontal adds. Same IEEE fp32 per element.
__global__ __launch_bounds__(512) void gru_kernel(
    const int* __restrict__ x,
    const float* __restrict__ mels_up,
    const float* __restrict__ w_ih,
    const float* __restrict__ w_hh,
    const float* __restrict__ b_ih,
    const float* __restrict__ b_hh,
    const ushort_t* __restrict__ w_ihT,
    uint32_t* __restrict__ h_ring,  // [16][16][512] fp32 bits
    ushort_t* __restrict__ h_seq)   // [16][3300][512] bf16
{
  int blk = blockIdx.x;
  int xcd = blk & 7, slot = blk >> 3;
  int b = (xcd << 1) | (slot >> 4);   // XCD-spread heuristic only; correctness agnostic
  int j = slot & 15;
  int tid = threadIdx.x;
  int cc = tid & 31, rr = tid >> 5;

  __shared__ __align__(16) float v[640];    // [0,512)=h, [512,592)=mel, rest 0
  __shared__ float embs[96];

  if (tid < 48) v[592 + tid] = 0.f;

  // ---- load resident weights (packed as float2 column pairs) ----
  f32x2 wp[6][10];
  float wmel[2][3];
  float bsum[4], bihn[2], bhhn[2];
  #pragma unroll
  for (int q = 0; q < 6; ++q) {
    int gate = q >> 1, kk = q & 1;
    int g = gate * 512 + j * 32 + rr * 2 + kk;
    #pragma unroll
    for (int cl = 0; cl < 10; ++cl) {
      #pragma unroll
      for (int e = 0; e < 2; ++e) {
        int col = cc * 20 + cl * 2 + e;
        float wv = 0.f;
        if (col < 512) wv = w_hh[g * 512 + col];
        else if (col < 592 && gate < 2) wv = w_ih[g * 592 + col]; // mel weights (r,z only)
        wp[q][cl][e] = wv;
      }
    }
  }
  #pragma unroll
  for (int kk = 0; kk < 2; ++kk) {
    int g = 1024 + j * 32 + rr * 2 + kk;
    #pragma unroll
    for (int ii = 0; ii < 3; ++ii) {
      int fidx = cc * 3 + ii;
      wmel[kk][ii] = (fidx < 80) ? w_ih[g * 592 + 512 + fidx] : 0.f;
    }
    bihn[kk] = b_ih[g];
    bhhn[kk] = b_hh[g];
  }
  #pragma unroll
  for (int q = 0; q < 4; ++q) {
    int gate = q >> 1, kk = q & 1;
    int g = gate * 512 + j * 32 + rr * 2 + kk;
    bsum[q] = b_ih[g] + b_hh[g];
  }

  for (int t = 0; t < T_SEQ; ++t) {
    // ---- prefetch (independent of h; plain cached loads) ----
    float melv = 0.f;
    if (tid < 80) melv = mels_up[(b * 80 + tid) * T_SEQ + t];
    float embv = 0.f;
    if (tid < 96) {
      int xv = x[b * T_SEQ + t];
      int gate = tid >> 5, kl = tid & 31;
      embv = b2f(w_ihT[xv * 1536 + gate * 512 + j * 32 + kl]);
    }
    // ---- poll h_{t-1} directly on data (sentinel = not ready) ----
    u64 q0 = 0, q1 = 0;
    if (t > 0 && tid < 128) {
      int rslot = (t - 1) & 15;
      const u64* src = (const u64*)&h_ring[((rslot * 16 + b) * 512) + tid * 4];
      // escape hatch: legit waits are <2 iters; exhaustion leaves NaN sentinels
      // in the output (visible absmax failure) instead of a hung container.
      for (int spin = 0; spin < 8192; ++spin) {
        q0 = __hip_atomic_load(src,     __ATOMIC_RELAXED, __HIP_MEMORY_SCOPE_AGENT);
        q1 = __hip_atomic_load(src + 1, __ATOMIC_RELAXED, __HIP_MEMORY_SCOPE_AGENT);
        if (((uint32_t)q0) != SENT && ((uint32_t)(q0 >> 32)) != SENT &&
            ((uint32_t)q1) != SENT && ((uint32_t)(q1 >> 32)) != SENT) break;
      }
    }
    // ---- stage v = [h | mel] and emb into LDS ----
    if (tid < 128) {
      ((u64*)v)[tid * 2]     = q0;   // t==0 -> zeros
      ((u64*)v)[tid * 2 + 1] = q1;
    }
    if (tid < 80) v[512 + tid] = melv;
    if (tid < 96) embs[tid] = embv;
    __syncthreads();

    // ---- matvec: acc[q] = sum_cols v[col]*W[row(q)][col], packed 2-wide ----
    f32x2 hp2[10];
    #pragma unroll
    for (int s = 0; s < 10; ++s) hp2[s] = *(const f32x2*)&v[cc * 20 + s * 2];
    f32x2 p0 = {0.f, 0.f}, p1 = {0.f, 0.f}, p2 = {0.f, 0.f};
    f32x2 p3 = {0.f, 0.f}, p4 = {0.f, 0.f}, p5 = {0.f, 0.f};
    #pragma unroll
    for (int cl = 0; cl < 10; ++cl) {
      f32x2 hvv = hp2[cl];
      asm("v_pk_fma_f32 %0, %1, %2, %0" : "+v"(p0) : "v"(hvv), "v"(wp[0][cl]));
      asm("v_pk_fma_f32 %0, %1, %2, %0" : "+v"(p1) : "v"(hvv), "v"(wp[1][cl]));
      asm("v_pk_fma_f32 %0, %1, %2, %0" : "+v"(p2) : "v"(hvv), "v"(wp[2][cl]));
      asm("v_pk_fma_f32 %0, %1, %2, %0" : "+v"(p3) : "v"(hvv), "v"(wp[3][cl]));
      asm("v_pk_fma_f32 %0, %1, %2, %0" : "+v"(p4) : "v"(hvv), "v"(wp[4][cl]));
      asm("v_pk_fma_f32 %0, %1, %2, %0" : "+v"(p5) : "v"(hvv), "v"(wp[5][cl]));
    }
    float a0 = p0[0] + p0[1], a1 = p1[0] + p1[1], a2 = p2[0] + p2[1];
    float a3 = p3[0] + p3[1], a4 = p4[0] + p4[1], a5 = p5[0] + p5[1];
    float am0 = 0.f, am1 = 0.f;   // n-gate x-side mel part (kept separate from h-side)
    #pragma unroll
    for (int ii = 0; ii < 3; ++ii) {
      float mv = v[512 + cc * 3 + ii];
      am0 += mv * wmel[0][ii]; am1 += mv * wmel[1][ii];
    }
    float r0 = red32(a0), r1 = red32(a1), r2 = red32(a2);
    float r3 = red32(a3), r4 = red32(a4), r5 = red32(a5);
    float rm0 = red32(am0), rm1 = red32(am1);

    if (cc == 15) {
      float hn2[2];
      #pragma unroll
      for (int kk = 0; kk < 2; ++kk) {
        float sr  = kk ? r1 : r0;
        float sz  = kk ? r3 : r2;
        float sn  = kk ? r5 : r4;
        float smn = kk ? rm1 : rm0;
        int k = rr * 2 + kk;
        float ar = embs[k] + sr + bsum[0 + kk];
        float az = embs[32 + k] + sz + bsum[2 + kk];
        float rg = 1.f / (1.f + __expf(-ar));
        float zg = 1.f / (1.f + __expf(-az));
        float xn = embs[64 + k] + smn + bihn[kk];
        float hn = sn + bhhn[kk];
        float na = xn + rg * hn;
        float e2 = __expf(2.f * na);
        float ng = 1.f - 2.f / (e2 + 1.f);   // tanh
        float hp = v[j * 32 + k];
        hn2[kk] = (1.f - zg) * ng + zg * hp;
      }
      // publish h_t: cache-bypassing relaxed agent store (no cache maintenance)
      int wslot = t & 15;
      u64 pk = ((u64)__float_as_uint(hn2[1]) << 32) | (u64)__float_as_uint(hn2[0]);
      u64* dst = (u64*)&h_ring[((wslot * 16 + b) * 512) + j * 32 + rr * 2];
      __hip_atomic_store(dst, pk, __ATOMIC_RELAXED, __HIP_MEMORY_SCOPE_AGENT);
      // re-arm slot t+8 (next written at t+8, last read at t-7: safe margin;
      // same-thread same-address ordering + per-step vmcnt drain at barrier)
      int aslot = (t + 8) & 15;
      u64* adst = (u64*)&h_ring[((aslot * 16 + b) * 512) + j * 32 + rr * 2];
      __hip_atomic_store(adst, SENTPAIR, __ATOMIC_RELAXED, __HIP_MEMORY_SCOPE_AGENT);
      // h_seq for the head (plain cached store; kernel boundary makes it visible)
      uint32_t hb = (uint32_t)f2b(hn2[0]) | ((uint32_t)f2b(hn2[1]) << 16);
      *(uint32_t*)&h_seq[(size_t)(b * T_SEQ + t) * 512 + j * 32 + rr * 2] = hb;
    }
    __syncthreads();   // v reused next step; also drains stores (vmcnt(0) at barrier)
  }
}

// ---------------- fused head: relu(h*fc1^T+b1)*fc2^T+b2 via bf16 MFMA -------
__global__ __launch_bounds__(512) void head_kernel(
    const ushort_t* __restrict__ h_seq,
    const ushort_t* __restrict__ fc1w,   // [n][k] bf16
    const ushort_t* __restrict__ fc2w,   // [n][k] bf16
    const float* __restrict__ fc1b,
    const float* __restrict__ fc2b,
    float* __restrict__ out) {
  __shared__ __align__(16) ushort_t h1[64 * 512];
  int blk = blockIdx.x;          // 825 blocks, 64 rows each
  int tid = threadIdx.x;
  int w = tid >> 6, l = tid & 63;
  int lm = l & 15, lq = l >> 4;
  int mt = w & 3;                // m-tile within the 64-row block
  int nb = (w >> 2) * 256;       // this wave's n-range
  int m0 = blk * 64;

  // stage 1: h1 = relu(h*fc1^T + b1)
  f32x4 acc[16];
  #pragma unroll
  for (int i = 0; i < 16; ++i) acc[i] = (f32x4){0.f, 0.f, 0.f, 0.f};
  const ushort_t* arow = h_seq + (size_t)(m0 + mt * 16 + lm) * 512;
  for (int kt = 0; kt < 16; ++kt) {
    short8 a = *(const short8*)(arow + kt * 32 + lq * 8);
    #pragma unroll
    for (int nt = 0; nt < 16; ++nt) {
      short8 bb = *(const short8*)(fc1w + (size_t)(nb + nt * 16 + lm) * 512 + kt * 32 + lq * 8);
      acc[nt] = __builtin_amdgcn_mfma_f32_16x16x32_bf16(a, bb, acc[nt], 0, 0, 0);
    }
  }
  #pragma unroll
  for (int nt = 0; nt < 16; ++nt) {
    int n = nb + nt * 16 + lm;
    float bias = fc1b[n];
    #pragma unroll
    for (int r = 0; r < 4; ++r) {
      int m = mt * 16 + lq * 4 + r;
      float vv = acc[nt][r] + bias;
      vv = fmaxf(vv, 0.f);
      h1[m * 512 + n] = f2b(vv);
    }
  }
  __syncthreads();
  // stage 2: out = h1*fc2^T + b2
  f32x4 acc2[16];
  #pragma unroll
  for (int i = 0; i < 16; ++i) acc2[i] = (f32x4){0.f, 0.f, 0.f, 0.f};
  for (int kt = 0; kt < 16; ++kt) {
    short8 a = *(const short8*)&h1[(mt * 16 + lm) * 512 + kt * 32 + lq * 8];
    #pragma unroll
    for (int nt = 0; nt < 16; ++nt) {
      short8 bb = *(const short8*)(fc2w + (size_t)(nb + nt * 16 + lm) * 512 + kt * 32 + lq * 8);
      acc2[nt] = __builtin_amdgcn_mfma_f32_16x16x32_bf16(a, bb, acc2[nt], 0, 0, 0);
    }
  }
  #pragma unroll
  for (int nt = 0; nt < 16; ++nt) {
    int n = nb + nt * 16 + lm;
    float bias = fc2b[n];
    #pragma unroll
    for (int r = 0; r < 4; ++r) {
      int m = mt * 16 + lq * 4 + r;
      out[(size_t)(m0 + m) * 512 + n] = acc2[nt][r] + bias;
    }
  }
}

// ---------------- launch -----------------------------------------------------
extern "C" void kernel_launch(void* const* d_in, const int* in_sizes, int n_in,
                              void* d_out, int out_size, void* d_ws, size_t ws_size,
                              hipStream_t stream) {
  (void)in_sizes; (void)n_in; (void)out_size; (void)ws_size;
  const int*   x    = (const int*)d_in[0];
  const float* mels = (const float*)d_in[1];
  const float* k0   = (const float*)d_in[2];
  const float* k1   = (const float*)d_in[3];
  const float* k2   = (const float*)d_in[4];
  const float* w_ih = (const float*)d_in[5];
  const float* w_hh = (const float*)d_in[6];
  const float* b_ih = (const float*)d_in[7];
  const float* b_hh = (const float*)d_in[8];
  const float* fc1w = (const float*)d_in[9];
  const float* fc1b = (const float*)d_in[10];
  const float* fc2w = (const float*)d_in[11];
  const float* fc2b = (const float*)d_in[12];

  char* ws = (char*)d_ws;
  float*    mels_up = (float*)(ws + 0);           // 16*80*3300*4  = 16,896,000
  ushort_t* h_seq   = (ushort_t*)(ws + 16896000); // 16*3300*512*2 = 54,067,200
  ushort_t* w_ihT   = (ushort_t*)(ws + 70963200); // 512*1536*2    =  1,572,864
  ushort_t* fc1wb   = (ushort_t*)(ws + 72536064); // 512*512*2     =    524,288
  ushort_t* fc2wb   = (ushort_t*)(ws + 73060352); // 512*512*2     =    524,288
  uint32_t* h_ring  = (uint32_t*)(ws + 73584640); // 16*16*512*4   =    524,288

  prep_kernel<<<5632, 256, 0, stream>>>(w_ih, fc1w, fc2w, w_ihT, fc1wb, fc2wb, h_ring);
  upsample_kernel<<<1280, 128, 0, stream>>>(mels, k0, k1, k2, mels_up);
  gru_kernel<<<256, 512, 0, stream>>>(x, mels_up, w_ih, w_hh, b_ih, b_hh, w_ihT,
                                      h_ring, h_seq);
  head_kernel<<<825, 512, 0, stream>>>(h_seq, fc1wb, fc2wb, fc1b, fc2b, (float*)d_out);
}